// Round 20
// baseline (333.808 us; speedup 1.0000x reference)
//
#include <hip/hip_runtime.h>
#include <math.h>

#define B_ 64
#define T_ 1024
#define D_ 768
#define A_ 128

typedef __attribute__((ext_vector_type(4))) float f32x4;
typedef __attribute__((ext_vector_type(8))) short s16x8;
typedef __attribute__((ext_vector_type(4))) short s16x4;

__device__ inline short f2b(float f) {
  union { float f; unsigned u; } v; v.f = f;
  unsigned r = (v.u + 0x7FFFu + ((v.u >> 16) & 1u)) >> 16;
  return (short)r;
}
__device__ inline float b2f(short s) {
  union { unsigned u; float f; } v; v.u = ((unsigned)(unsigned short)s) << 16;
  return v.f;
}

__device__ inline void gll16(const void* g, const void* lds) {
  __builtin_amdgcn_global_load_lds(
      (const __attribute__((address_space(1))) unsigned*)g,
      (__attribute__((address_space(3))) unsigned*)lds, 16, 0, 0);
}

// non-temporal 16B store (write-only streams: no L2 allocation pressure)
__device__ inline void nts16x8(short* p, s16x8 v) {
  __builtin_nontemporal_store(v, (s16x8*)p);
}

// ---------------------------------------------------------------------------
// G4: 256x256-tile, BK=64, 8-wave, fused 4-phase counted-vmcnt bf16 GEMM
// (R13 schedule + R19 NT out-writes). out[s,d]=(sum_t E[s,t]*xt[d,t])/rs[s].
// ---------------------------------------------------------------------------
__global__ __launch_bounds__(512, 2)
void g4_div(const short* __restrict__ Ag, const short* __restrict__ Bg,
            const float* __restrict__ Rs, float* __restrict__ Cg) {
  __shared__ __align__(16) short AS[2][16384];
  __shared__ __align__(16) short BS[2][16384];
  unsigned nwg = gridDim.x;
  unsigned L = blockIdx.x;
  unsigned xcd = L & 7u, base = L >> 3;
  unsigned q = nwg >> 3, r = nwg & 7u;
  unsigned id = (xcd < r ? xcd * (q + 1) : r * (q + 1) + (xcd - r) * q) + base;
  const int bz = id / 12;
  const int rem = id - bz * 12;
  const int by = rem / 3, bx = rem - (rem / 3) * 3;
  const int m0 = by * 256, n0 = bx * 256;

  const short* Ab = Ag + (size_t)bz * (T_ * T_);
  const short* Bb = Bg + (size_t)bz * (D_ * T_);
  const float* rsb = Rs + (size_t)bz * T_;
  float* Cb = Cg + (size_t)bz * (T_ * D_);

  const int tid = threadIdx.x;
  const int w = tid >> 6, lane = tid & 63;
  const int wr = w >> 2, wc = w & 3;
  const int lr = lane & 15, lq = lane >> 4;
  const int swzk = (lane & 7) ^ ((lane >> 3) & 7);
  const int abase = (wr * 128 + lr) * 64;
  const int bbase = (wc * 64 + lr) * 64;
  const int sx = lr & 7;
  const int sl0 = (lq ^ sx) * 8;
  const int sl1 = ((4 + lq) ^ sx) * 8;

  f32x4 acc[8][4] = {};
  s16x8 bq[4][2];

#define STG(dst, src, r0, kt)                                                  \
  { _Pragma("unroll")                                                          \
    for (int jj = 0; jj < 2; ++jj) {                                           \
      int rr = jj * 64 + w * 8 + (lane >> 3);                                  \
      gll16((src) + (size_t)((r0) + rr) * 1024 + (kt) + swzk * 8,              \
            (dst) + jj * 4096 + w * 512);                                      \
    } }

#define PH2(P, Q0, VM, ...)                                                    \
  {                                                                            \
    s16x8 a0_ = *(const s16x8*)&AS[P][abase + (2 * (Q0)) * 1024 + sl0];        \
    s16x8 a1_ = *(const s16x8*)&AS[P][abase + (2 * (Q0)) * 1024 + sl1];        \
    s16x8 a2_ = *(const s16x8*)&AS[P][abase + (2 * (Q0) + 1) * 1024 + sl0];    \
    s16x8 a3_ = *(const s16x8*)&AS[P][abase + (2 * (Q0) + 1) * 1024 + sl1];    \
    if ((Q0) == 0) {                                                           \
      _Pragma("unroll")                                                        \
      for (int nf = 0; nf < 4; ++nf) {                                         \
        bq[nf][0] = *(const s16x8*)&BS[P][bbase + nf * 1024 + sl0];            \
        bq[nf][1] = *(const s16x8*)&BS[P][bbase + nf * 1024 + sl1];            \
      }                                                                        \
    }                                                                          \
    __VA_ARGS__;                                                               \
    VM;                                                                        \
    __builtin_amdgcn_s_barrier();                                              \
    asm volatile("s_waitcnt lgkmcnt(0)" ::: "memory");                         \
    __builtin_amdgcn_s_setprio(1);                                             \
    _Pragma("unroll")                                                          \
    for (int nf = 0; nf < 4; ++nf) {                                           \
      acc[2*(Q0)][nf]   = __builtin_amdgcn_mfma_f32_16x16x32_bf16(a0_, bq[nf][0], acc[2*(Q0)][nf], 0, 0, 0);   \
      acc[2*(Q0)+1][nf] = __builtin_amdgcn_mfma_f32_16x16x32_bf16(a2_, bq[nf][0], acc[2*(Q0)+1][nf], 0, 0, 0); \
    }                                                                          \
    s16x8 a4_ = *(const s16x8*)&AS[P][abase + (2 * (Q0) + 2) * 1024 + sl0];    \
    s16x8 a5_ = *(const s16x8*)&AS[P][abase + (2 * (Q0) + 2) * 1024 + sl1];    \
    s16x8 a6_ = *(const s16x8*)&AS[P][abase + (2 * (Q0) + 3) * 1024 + sl0];    \
    s16x8 a7_ = *(const s16x8*)&AS[P][abase + (2 * (Q0) + 3) * 1024 + sl1];    \
    _Pragma("unroll")                                                          \
    for (int nf = 0; nf < 4; ++nf) {                                           \
      acc[2*(Q0)][nf]   = __builtin_amdgcn_mfma_f32_16x16x32_bf16(a1_, bq[nf][1], acc[2*(Q0)][nf], 0, 0, 0);   \
      acc[2*(Q0)+1][nf] = __builtin_amdgcn_mfma_f32_16x16x32_bf16(a3_, bq[nf][1], acc[2*(Q0)+1][nf], 0, 0, 0); \
    }                                                                          \
    _Pragma("unroll")                                                          \
    for (int nf = 0; nf < 4; ++nf) {                                           \
      acc[2*(Q0)+2][nf] = __builtin_amdgcn_mfma_f32_16x16x32_bf16(a4_, bq[nf][0], acc[2*(Q0)+2][nf], 0, 0, 0); \
      acc[2*(Q0)+3][nf] = __builtin_amdgcn_mfma_f32_16x16x32_bf16(a6_, bq[nf][0], acc[2*(Q0)+3][nf], 0, 0, 0); \
    }                                                                          \
    _Pragma("unroll")                                                          \
    for (int nf = 0; nf < 4; ++nf) {                                           \
      acc[2*(Q0)+2][nf] = __builtin_amdgcn_mfma_f32_16x16x32_bf16(a5_, bq[nf][1], acc[2*(Q0)+2][nf], 0, 0, 0); \
      acc[2*(Q0)+3][nf] = __builtin_amdgcn_mfma_f32_16x16x32_bf16(a7_, bq[nf][1], acc[2*(Q0)+3][nf], 0, 0, 0); \
    }                                                                          \
    __builtin_amdgcn_s_setprio(0);                                             \
    __builtin_amdgcn_s_barrier();                                              \
  }

#define VM4 asm volatile("s_waitcnt vmcnt(4)" ::: "memory")
#define VM0 asm volatile("s_waitcnt vmcnt(0)" ::: "memory")
#define NOP (void)0

  STG(&BS[0][0],    Bb, n0,       0);
  STG(&BS[0][8192], Bb, n0 + 128, 0);
  STG(&AS[0][0],    Ab, m0,       0);
  STG(&AS[0][8192], Ab, m0 + 128, 0);
  STG(&BS[1][0],    Bb, n0,       64);
  STG(&BS[1][8192], Bb, n0 + 128, 64);
  VM4;
  __builtin_amdgcn_s_barrier();

  for (int j = 0; j < 7; ++j) {
    const int kb = j * 128;
    PH2(0, 0, NOP,
        STG(&AS[1][0],    Ab, m0,       kb + 64);
        STG(&AS[1][8192], Ab, m0 + 128, kb + 64));
    PH2(0, 2, VM4,
        STG(&BS[0][0],    Bb, n0,       kb + 128);
        STG(&BS[0][8192], Bb, n0 + 128, kb + 128));
    PH2(1, 0, NOP,
        STG(&AS[0][0],    Ab, m0,       kb + 128);
        STG(&AS[0][8192], Ab, m0 + 128, kb + 128));
    PH2(1, 2, VM4,
        STG(&BS[1][0],    Bb, n0,       kb + 192);
        STG(&BS[1][8192], Bb, n0 + 128, kb + 192));
  }
  PH2(0, 0, NOP,
      STG(&AS[1][0],    Ab, m0,       960);
      STG(&AS[1][8192], Ab, m0 + 128, 960));
  PH2(0, 2, VM0, NOP);
  PH2(1, 0, NOP, NOP);
  PH2(1, 2, NOP, NOP);

#undef STG
#undef PH2
#undef VM4
#undef VM0
#undef NOP

#pragma unroll
  for (int mf = 0; mf < 8; ++mf) {
    f32x4 rsv = *(const f32x4*)&rsb[m0 + wr * 128 + mf * 16 + lq * 4];
    f32x4 inv;
#pragma unroll
    for (int qq = 0; qq < 4; ++qq) {
      float iv;
      asm("v_rcp_f32 %0, %1" : "=v"(iv) : "v"(rsv[qq]));
      inv[qq] = iv;
    }
#pragma unroll
    for (int nf = 0; nf < 4; ++nf) {
      int m = m0 + wr * 128 + mf * 16 + lq * 4;
      int n = n0 + wc * 64 + nf * 16 + lr;
#pragma unroll
      for (int qq = 0; qq < 4; ++qq)
        __builtin_nontemporal_store(acc[mf][nf][qq] * inv[qq],
                                    &Cb[(size_t)(m + qq) * D_ + n]);
    }
  }
}

// ---------------------------------------------------------------------------
// g12: FUSED G1+G2. R20: s-loop rebuilt with DIRECT NT St stores — bounce +
// St-copy phases deleted, 2 barriers per s-tile (was 4). Per wave & (mf,nf)
// the four lq-lanes cover 16 contiguous t = 32B full sectors per s-row, so
// direct s16x4 stores keep full sector utilization (unlike R9's 8B@2KB).
// The exp/store tail touches no LDS, so it overlaps the next tile's staging.
// Main loop unchanged from R16/R19 (best measured).
// ---------------------------------------------------------------------------
__global__ __launch_bounds__(512, 4)
void g12(const short* __restrict__ W1tg, const float* __restrict__ xg,
         const short* __restrict__ W2tg, short* __restrict__ Stg,
         float* __restrict__ rsg, short* __restrict__ xtg, int nb) {
  __shared__ __align__(16) short SMEM[33792];
  short* As = SMEM;
  short* Bs = SMEM + 8192;
  short* Ts = SMEM + 16384;
  short* Hs = SMEM;
  short* B2 = SMEM + 16384;

  unsigned nwg = gridDim.x;
  unsigned L = blockIdx.x;
  unsigned xcd = L & 7u, base = L >> 3;
  unsigned q = nwg >> 3, r = nwg & 7u;
  unsigned id = (xcd < r ? xcd * (q + 1) : r * (q + 1) + (xcd - r) * q) + base;
  const int bz = id >> 3, bt = id & 7;
  const int t0 = bt * 128;

  const float* xb = xg + (size_t)bz * T_ * D_;
  short* Xtb = xtg + (size_t)bz * ((size_t)D_ * T_);
  short* Stb = Stg + (size_t)bz * (T_ * T_);
  float* rsb = rsg + (size_t)bz * T_;

  const int tid = threadIdx.x;
  const int w = tid >> 6, lane = tid & 63;
  const int wva = w >> 2, wvt = w & 3;
  const int lr = lane & 15, lq = lane >> 4;
  const int swzk = (lane & 7) ^ ((lane >> 3) & 7);
  const int sxl = lr & 7;
  const int sl0 = (lq ^ sxl) * 8;
  const int sl1 = ((4 + lq) ^ sxl) * 8;

  f32x4 acc[4][2] = {};

  float4 xf0[2], xf1[2];
#pragma unroll
  for (int u = 0; u < 2; ++u) {
    int c = tid * 2 + u;
    int row = c >> 3, k8 = c & 7;
    const float* gp = xb + (size_t)(t0 + row) * D_ + k8 * 8;
    xf0[u] = *(const float4*)gp;
    xf1[u] = *(const float4*)(gp + 4);
  }

  for (int k0 = 0; k0 < D_; k0 += 64) {
    __syncthreads();
#pragma unroll
    for (int u = 0; u < 2; ++u) {
      int c = tid * 2 + u;
      int row = c >> 3, k8 = c & 7;
      s16x8 p;
      p[0] = f2b(xf0[u].x); p[1] = f2b(xf0[u].y);
      p[2] = f2b(xf0[u].z); p[3] = f2b(xf0[u].w);
      p[4] = f2b(xf1[u].x); p[5] = f2b(xf1[u].y);
      p[6] = f2b(xf1[u].z); p[7] = f2b(xf1[u].w);
      *(s16x8*)&Bs[row * 64 + ((k8 ^ (row & 7)) << 3)] = p;
#pragma unroll
      for (int j = 0; j < 8; ++j) {
        int d = k8 * 8 + j;
        Ts[d * 136 + (row ^ (d & 32))] = p[j];
      }
    }
#pragma unroll
    for (int i = 0; i < 2; ++i) {
      int chunk = w * 2 + i;
      int row = chunk * 8 + (lane >> 3);
      gll16(W1tg + (size_t)row * D_ + k0 + swzk * 8, As + chunk * 512);
    }
    __syncthreads();
    if (k0 + 64 < D_) {
#pragma unroll
      for (int u = 0; u < 2; ++u) {
        int c = tid * 2 + u;
        int row = c >> 3, k8 = c & 7;
        const float* gp = xb + (size_t)(t0 + row) * D_ + (k0 + 64) + k8 * 8;
        xf0[u] = *(const float4*)gp;
        xf1[u] = *(const float4*)(gp + 4);
      }
    }
#pragma unroll
    for (int kk = 0; kk < 2; ++kk) {
      const int sl = kk ? sl1 : sl0;
      s16x8 a[4], b[2];
#pragma unroll
      for (int mf = 0; mf < 4; ++mf)
        a[mf] = *(const s16x8*)&As[(wva * 64 + mf * 16 + lr) * 64 + sl];
#pragma unroll
      for (int nf = 0; nf < 2; ++nf)
        b[nf] = *(const s16x8*)&Bs[(wvt * 32 + nf * 16 + lr) * 64 + sl];
#pragma unroll
      for (int mf = 0; mf < 4; ++mf)
#pragma unroll
        for (int nf = 0; nf < 2; ++nf)
          acc[mf][nf] = __builtin_amdgcn_mfma_f32_16x16x32_bf16(
              a[mf], b[nf], acc[mf][nf], 0, 0, 0);
    }
#pragma unroll
    for (int u = 0; u < 2; ++u) {
      int task = tid + u * 512;
      int dd = task >> 4, t8 = task & 15;
      nts16x8(&Xtb[(size_t)(k0 + dd) * T_ + t0 + t8 * 8],
              *(const s16x8*)&Ts[dd * 136 + ((t8 ^ ((dd >> 3) & 4)) << 3)]);
    }
  }

  __syncthreads();
#pragma unroll
  for (int mf = 0; mf < 4; ++mf)
#pragma unroll
    for (int nf = 0; nf < 2; ++nf) {
      int ml = wva * 64 + mf * 16 + lq * 4;
      int nl = wvt * 32 + nf * 16 + lr;
      s16x4 pk;
#pragma unroll
      for (int qq = 0; qq < 4; ++qq) pk[qq] = f2b(tanhf(acc[mf][nf][qq]));
      int slot = (ml >> 3) ^ (nl & 7);
      *(s16x4*)&Hs[nl * 128 + (slot << 3) + (ml & 7)] = pk;
    }
  __syncthreads();

  // -------- s-loop: E = exp(H @ W2t^T), 8 s-tiles, 2 barriers each --------
  const int wvt2 = w >> 2, wvs = w & 3;
  for (int si = 0; si < 8; ++si) {
    const int s0 = si * 128;
#pragma unroll
    for (int i = 0; i < 4; ++i) {
      int c = w * 4 + i;
      int row = 4 * c + (lane >> 4);
      gll16(W2tg + (size_t)(s0 + row) * A_ + (((lane & 15) ^ (row & 7)) << 3),
            B2 + c * 512);
    }
    __syncthreads();                       // B2 staged
    f32x4 ac2[4][2] = {};
#pragma unroll
    for (int kk = 0; kk < 4; ++kk) {
      s16x8 a[4], b[2];
#pragma unroll
      for (int mf = 0; mf < 4; ++mf) {
        int row = wvt2 * 64 + mf * 16 + lr;
        a[mf] = *(const s16x8*)&Hs[row * 128 + (((kk * 4 + lq) ^ sxl) << 3)];
      }
#pragma unroll
      for (int nf = 0; nf < 2; ++nf) {
        int row = wvs * 32 + nf * 16 + lr;
        b[nf] = *(const s16x8*)&B2[row * 128 + (((kk * 4 + lq) ^ sxl) << 3)];
      }
#pragma unroll
      for (int mf = 0; mf < 4; ++mf)
#pragma unroll
        for (int nf = 0; nf < 2; ++nf)
          ac2[mf][nf] = __builtin_amdgcn_mfma_f32_16x16x32_bf16(
              a[mf], b[nf], ac2[mf][nf], 0, 0, 0);
    }
    __syncthreads();                       // B2 reads done (next stage safe)
    // exp + psum + DIRECT NT St stores (no LDS -> overlaps next staging)
    float psum[2] = {0.f, 0.f};
#pragma unroll
    for (int mf = 0; mf < 4; ++mf)
#pragma unroll
      for (int nf = 0; nf < 2; ++nf) {
        int s = s0 + wvs * 32 + nf * 16 + lr;           // global s row
        int t = t0 + wvt2 * 64 + mf * 16 + lq * 4;      // 4 contiguous t
        s16x4 pk;
#pragma unroll
        for (int qq = 0; qq < 4; ++qq) {
          float v = __expf(ac2[mf][nf][qq]);
          pk[qq] = f2b(v);
          psum[nf] += b2f(pk[qq]);                      // sum ROUNDED values
        }
        __builtin_nontemporal_store(pk, (s16x4*)&Stb[(size_t)s * T_ + t]);
      }
#pragma unroll
    for (int nf = 0; nf < 2; ++nf) {
      psum[nf] += __shfl_xor(psum[nf], 16);
      psum[nf] += __shfl_xor(psum[nf], 32);
    }
    if (lq == 0) {
#pragma unroll
      for (int nf = 0; nf < 2; ++nf)
        atomicAdd(&rsb[s0 + wvs * 32 + nf * 16 + lr], psum[nf]);
    }
  }
}

// ---------------------------------------------------------------------------
// transpose + fp32->bf16 (W1/W2 only).
// ---------------------------------------------------------------------------
__global__ __launch_bounds__(256)
void transpose_cvt(const float* __restrict__ src, short* __restrict__ dst,
                   int R, int C) {
  __shared__ float sh[64][65];
  const int tid = threadIdx.x;
  const float* s = src + (size_t)blockIdx.z * R * C;
  short* d = dst + (size_t)blockIdx.z * R * C;
  const int r0 = blockIdx.y * 64, c0 = blockIdx.x * 64;
#pragma unroll
  for (int u = 0; u < 4; ++u) {
    int e = tid + u * 256;
    int rr = e >> 4, cc4 = (e & 15) * 4;
    float4 v = *(const float4*)&s[(size_t)(r0 + rr) * C + c0 + cc4];
    sh[rr][cc4 + 0] = v.x;
    sh[rr][cc4 + 1] = v.y;
    sh[rr][cc4 + 2] = v.z;
    sh[rr][cc4 + 3] = v.w;
  }
  __syncthreads();
#pragma unroll
  for (int u = 0; u < 4; ++u) {
    int e = tid + u * 256;
    int dr = e >> 4, tc4 = (e & 15) * 4;
    s16x4 pk;
#pragma unroll
    for (int j = 0; j < 4; ++j) pk[j] = f2b(sh[tc4 + j][dr]);
    *(s16x4*)&d[(size_t)(c0 + dr) * R + r0 + tc4] = pk;
  }
}

extern "C" void kernel_launch(void* const* d_in, const int* in_sizes, int n_in,
                              void* d_out, int out_size, void* d_ws, size_t ws_size,
                              hipStream_t stream) {
  const float* x  = (const float*)d_in[0];   // [B,T,D]
  const float* W1 = (const float*)d_in[1];   // [D,A]
  const float* W2 = (const float*)d_in[2];   // [A,T]
  float* out = (float*)d_out;                // [B,T,D] fp32

  // ws (shorts): xt[B,D,T] | W1t[A,D] | W2t[T,A] | rs[B*T fp32] | St[nb,T,T]
  short* xt  = (short*)d_ws;
  short* W1t = xt + (size_t)B_ * D_ * T_;
  short* W2t = W1t + (size_t)A_ * D_;
  float* rs  = (float*)(W2t + (size_t)T_ * A_);
  short* St  = (short*)(rs + (size_t)B_ * T_);
  size_t fixed_bytes = (size_t)((char*)St - (char*)xt);
  long avail = (long)ws_size - (long)fixed_bytes;
  long per_b = (long)T_ * T_ * sizeof(short);
  int chunk = (int)(avail > 0 ? avail / per_b : 0);
  if (chunk > B_) chunk = B_;
  if (chunk < 1) chunk = 1;

  hipMemsetAsync(rs, 0, (size_t)B_ * T_ * sizeof(float), stream);

  transpose_cvt<<<dim3(A_ / 64, D_ / 64, 1), 256, 0, stream>>>(W1, W1t, D_, A_);
  transpose_cvt<<<dim3(T_ / 64, A_ / 64, 1), 256, 0, stream>>>(W2, W2t, A_, T_);

  for (int b0 = 0; b0 < B_; b0 += chunk) {
    int nb = B_ - b0; if (nb > chunk) nb = chunk;
    g12<<<8 * nb, 512, 0, stream>>>(
        W1t, x + (size_t)b0 * T_ * D_, W2t, St,
        rs + (size_t)b0 * T_, xt + (size_t)b0 * (size_t)D_ * T_, nb);
    g4_div<<<12 * nb, 512, 0, stream>>>(
        St, xt + (size_t)b0 * (size_t)D_ * T_, rs + (size_t)b0 * T_,
        out + (size_t)b0 * (size_t)T_ * D_);
  }
}

// Round 21
// 246.557 us; speedup vs baseline: 1.3539x; 1.3539x over previous
//
#include <hip/hip_runtime.h>
#include <math.h>

#define B_ 64
#define T_ 1024
#define D_ 768
#define A_ 128

typedef __attribute__((ext_vector_type(4))) float f32x4;
typedef __attribute__((ext_vector_type(8))) short s16x8;
typedef __attribute__((ext_vector_type(4))) short s16x4;

__device__ inline short f2b(float f) {
  union { float f; unsigned u; } v; v.f = f;
  unsigned r = (v.u + 0x7FFFu + ((v.u >> 16) & 1u)) >> 16;
  return (short)r;
}
__device__ inline float b2f(short s) {
  union { unsigned u; float f; } v; v.u = ((unsigned)(unsigned short)s) << 16;
  return v.f;
}

__device__ inline void gll16(const void* g, const void* lds) {
  __builtin_amdgcn_global_load_lds(
      (const __attribute__((address_space(1))) unsigned*)g,
      (__attribute__((address_space(3))) unsigned*)lds, 16, 0, 0);
}

// non-temporal 16B store (write-only streams, FULL-segment only — R20 showed
// 8B NT scatter causes HBM read-modify-write amplification: WRITE 233->350MB)
__device__ inline void nts16x8(short* p, s16x8 v) {
  __builtin_nontemporal_store(v, (s16x8*)p);
}

// ---------------------------------------------------------------------------
// G4: 256x256-tile, BK=64, 8-wave, fused 4-phase counted-vmcnt bf16 GEMM
// (R13 schedule + NT out-writes). out[s,d]=(sum_t E[s,t]*xt[d,t])/rs[s].
// ---------------------------------------------------------------------------
__global__ __launch_bounds__(512, 2)
void g4_div(const short* __restrict__ Ag, const short* __restrict__ Bg,
            const float* __restrict__ Rs, float* __restrict__ Cg) {
  __shared__ __align__(16) short AS[2][16384];
  __shared__ __align__(16) short BS[2][16384];
  unsigned nwg = gridDim.x;
  unsigned L = blockIdx.x;
  unsigned xcd = L & 7u, base = L >> 3;
  unsigned q = nwg >> 3, r = nwg & 7u;
  unsigned id = (xcd < r ? xcd * (q + 1) : r * (q + 1) + (xcd - r) * q) + base;
  const int bz = id / 12;
  const int rem = id - bz * 12;
  const int by = rem / 3, bx = rem - (rem / 3) * 3;
  const int m0 = by * 256, n0 = bx * 256;

  const short* Ab = Ag + (size_t)bz * (T_ * T_);
  const short* Bb = Bg + (size_t)bz * (D_ * T_);
  const float* rsb = Rs + (size_t)bz * T_;
  float* Cb = Cg + (size_t)bz * (T_ * D_);

  const int tid = threadIdx.x;
  const int w = tid >> 6, lane = tid & 63;
  const int wr = w >> 2, wc = w & 3;
  const int lr = lane & 15, lq = lane >> 4;
  const int swzk = (lane & 7) ^ ((lane >> 3) & 7);
  const int abase = (wr * 128 + lr) * 64;
  const int bbase = (wc * 64 + lr) * 64;
  const int sx = lr & 7;
  const int sl0 = (lq ^ sx) * 8;
  const int sl1 = ((4 + lq) ^ sx) * 8;

  f32x4 acc[8][4] = {};
  s16x8 bq[4][2];

#define STG(dst, src, r0, kt)                                                  \
  { _Pragma("unroll")                                                          \
    for (int jj = 0; jj < 2; ++jj) {                                           \
      int rr = jj * 64 + w * 8 + (lane >> 3);                                  \
      gll16((src) + (size_t)((r0) + rr) * 1024 + (kt) + swzk * 8,              \
            (dst) + jj * 4096 + w * 512);                                      \
    } }

#define PH2(P, Q0, VM, ...)                                                    \
  {                                                                            \
    s16x8 a0_ = *(const s16x8*)&AS[P][abase + (2 * (Q0)) * 1024 + sl0];        \
    s16x8 a1_ = *(const s16x8*)&AS[P][abase + (2 * (Q0)) * 1024 + sl1];        \
    s16x8 a2_ = *(const s16x8*)&AS[P][abase + (2 * (Q0) + 1) * 1024 + sl0];    \
    s16x8 a3_ = *(const s16x8*)&AS[P][abase + (2 * (Q0) + 1) * 1024 + sl1];    \
    if ((Q0) == 0) {                                                           \
      _Pragma("unroll")                                                        \
      for (int nf = 0; nf < 4; ++nf) {                                         \
        bq[nf][0] = *(const s16x8*)&BS[P][bbase + nf * 1024 + sl0];            \
        bq[nf][1] = *(const s16x8*)&BS[P][bbase + nf * 1024 + sl1];            \
      }                                                                        \
    }                                                                          \
    __VA_ARGS__;                                                               \
    VM;                                                                        \
    __builtin_amdgcn_s_barrier();                                              \
    asm volatile("s_waitcnt lgkmcnt(0)" ::: "memory");                         \
    __builtin_amdgcn_s_setprio(1);                                             \
    _Pragma("unroll")                                                          \
    for (int nf = 0; nf < 4; ++nf) {                                           \
      acc[2*(Q0)][nf]   = __builtin_amdgcn_mfma_f32_16x16x32_bf16(a0_, bq[nf][0], acc[2*(Q0)][nf], 0, 0, 0);   \
      acc[2*(Q0)+1][nf] = __builtin_amdgcn_mfma_f32_16x16x32_bf16(a2_, bq[nf][0], acc[2*(Q0)+1][nf], 0, 0, 0); \
    }                                                                          \
    s16x8 a4_ = *(const s16x8*)&AS[P][abase + (2 * (Q0) + 2) * 1024 + sl0];    \
    s16x8 a5_ = *(const s16x8*)&AS[P][abase + (2 * (Q0) + 2) * 1024 + sl1];    \
    s16x8 a6_ = *(const s16x8*)&AS[P][abase + (2 * (Q0) + 3) * 1024 + sl0];    \
    s16x8 a7_ = *(const s16x8*)&AS[P][abase + (2 * (Q0) + 3) * 1024 + sl1];    \
    _Pragma("unroll")                                                          \
    for (int nf = 0; nf < 4; ++nf) {                                           \
      acc[2*(Q0)][nf]   = __builtin_amdgcn_mfma_f32_16x16x32_bf16(a1_, bq[nf][1], acc[2*(Q0)][nf], 0, 0, 0);   \
      acc[2*(Q0)+1][nf] = __builtin_amdgcn_mfma_f32_16x16x32_bf16(a3_, bq[nf][1], acc[2*(Q0)+1][nf], 0, 0, 0); \
    }                                                                          \
    _Pragma("unroll")                                                          \
    for (int nf = 0; nf < 4; ++nf) {                                           \
      acc[2*(Q0)+2][nf] = __builtin_amdgcn_mfma_f32_16x16x32_bf16(a4_, bq[nf][0], acc[2*(Q0)+2][nf], 0, 0, 0); \
      acc[2*(Q0)+3][nf] = __builtin_amdgcn_mfma_f32_16x16x32_bf16(a6_, bq[nf][0], acc[2*(Q0)+3][nf], 0, 0, 0); \
    }                                                                          \
    _Pragma("unroll")                                                          \
    for (int nf = 0; nf < 4; ++nf) {                                           \
      acc[2*(Q0)+2][nf] = __builtin_amdgcn_mfma_f32_16x16x32_bf16(a5_, bq[nf][1], acc[2*(Q0)+2][nf], 0, 0, 0); \
      acc[2*(Q0)+3][nf] = __builtin_amdgcn_mfma_f32_16x16x32_bf16(a7_, bq[nf][1], acc[2*(Q0)+3][nf], 0, 0, 0); \
    }                                                                          \
    __builtin_amdgcn_s_setprio(0);                                             \
    __builtin_amdgcn_s_barrier();                                              \
  }

#define VM4 asm volatile("s_waitcnt vmcnt(4)" ::: "memory")
#define VM0 asm volatile("s_waitcnt vmcnt(0)" ::: "memory")
#define NOP (void)0

  STG(&BS[0][0],    Bb, n0,       0);
  STG(&BS[0][8192], Bb, n0 + 128, 0);
  STG(&AS[0][0],    Ab, m0,       0);
  STG(&AS[0][8192], Ab, m0 + 128, 0);
  STG(&BS[1][0],    Bb, n0,       64);
  STG(&BS[1][8192], Bb, n0 + 128, 64);
  VM4;
  __builtin_amdgcn_s_barrier();

  for (int j = 0; j < 7; ++j) {
    const int kb = j * 128;
    PH2(0, 0, NOP,
        STG(&AS[1][0],    Ab, m0,       kb + 64);
        STG(&AS[1][8192], Ab, m0 + 128, kb + 64));
    PH2(0, 2, VM4,
        STG(&BS[0][0],    Bb, n0,       kb + 128);
        STG(&BS[0][8192], Bb, n0 + 128, kb + 128));
    PH2(1, 0, NOP,
        STG(&AS[0][0],    Ab, m0,       kb + 128);
        STG(&AS[0][8192], Ab, m0 + 128, kb + 128));
    PH2(1, 2, VM4,
        STG(&BS[1][0],    Bb, n0,       kb + 192);
        STG(&BS[1][8192], Bb, n0 + 128, kb + 192));
  }
  PH2(0, 0, NOP,
      STG(&AS[1][0],    Ab, m0,       960);
      STG(&AS[1][8192], Ab, m0 + 128, 960));
  PH2(0, 2, VM0, NOP);
  PH2(1, 0, NOP, NOP);
  PH2(1, 2, NOP, NOP);

#undef STG
#undef PH2
#undef VM4
#undef VM0
#undef NOP

#pragma unroll
  for (int mf = 0; mf < 8; ++mf) {
    f32x4 rsv = *(const f32x4*)&rsb[m0 + wr * 128 + mf * 16 + lq * 4];
    f32x4 inv;
#pragma unroll
    for (int qq = 0; qq < 4; ++qq) {
      float iv;
      asm("v_rcp_f32 %0, %1" : "=v"(iv) : "v"(rsv[qq]));
      inv[qq] = iv;
    }
#pragma unroll
    for (int nf = 0; nf < 4; ++nf) {
      int m = m0 + wr * 128 + mf * 16 + lq * 4;
      int n = n0 + wc * 64 + nf * 16 + lr;
#pragma unroll
      for (int qq = 0; qq < 4; ++qq)
        __builtin_nontemporal_store(acc[mf][nf][qq] * inv[qq],
                                    &Cb[(size_t)(m + qq) * D_ + n]);
    }
  }
}

// ---------------------------------------------------------------------------
// g12: FUSED G1+G2 (R19 version — best measured total 249.8us).
// 512 thr / 8 waves, 66KB LDS, 2 blocks/CU. xt + St bounce-coalesced NT
// writes (256B segments). s-loop: 4 barriers/s-tile with LDS bounce — R20's
// direct-store variant regressed (partial-sector NT writes).
// ---------------------------------------------------------------------------
__global__ __launch_bounds__(512, 4)
void g12(const short* __restrict__ W1tg, const float* __restrict__ xg,
         const short* __restrict__ W2tg, short* __restrict__ Stg,
         float* __restrict__ rsg, short* __restrict__ xtg, int nb) {
  __shared__ __align__(16) short SMEM[33792];
  short* As = SMEM;
  short* Bs = SMEM + 8192;
  short* Ts = SMEM + 16384;
  short* Hs = SMEM;
  short* B2 = SMEM + 16384;

  unsigned nwg = gridDim.x;
  unsigned L = blockIdx.x;
  unsigned xcd = L & 7u, base = L >> 3;
  unsigned q = nwg >> 3, r = nwg & 7u;
  unsigned id = (xcd < r ? xcd * (q + 1) : r * (q + 1) + (xcd - r) * q) + base;
  const int bz = id >> 3, bt = id & 7;
  const int t0 = bt * 128;

  const float* xb = xg + (size_t)bz * T_ * D_;
  short* Xtb = xtg + (size_t)bz * ((size_t)D_ * T_);
  short* Stb = Stg + (size_t)bz * (T_ * T_);
  float* rsb = rsg + (size_t)bz * T_;

  const int tid = threadIdx.x;
  const int w = tid >> 6, lane = tid & 63;
  const int wva = w >> 2, wvt = w & 3;
  const int lr = lane & 15, lq = lane >> 4;
  const int swzk = (lane & 7) ^ ((lane >> 3) & 7);
  const int sxl = lr & 7;
  const int sl0 = (lq ^ sxl) * 8;
  const int sl1 = ((4 + lq) ^ sxl) * 8;

  f32x4 acc[4][2] = {};

  float4 xf0[2], xf1[2];
#pragma unroll
  for (int u = 0; u < 2; ++u) {
    int c = tid * 2 + u;
    int row = c >> 3, k8 = c & 7;
    const float* gp = xb + (size_t)(t0 + row) * D_ + k8 * 8;
    xf0[u] = *(const float4*)gp;
    xf1[u] = *(const float4*)(gp + 4);
  }

  for (int k0 = 0; k0 < D_; k0 += 64) {
    __syncthreads();
#pragma unroll
    for (int u = 0; u < 2; ++u) {
      int c = tid * 2 + u;
      int row = c >> 3, k8 = c & 7;
      s16x8 p;
      p[0] = f2b(xf0[u].x); p[1] = f2b(xf0[u].y);
      p[2] = f2b(xf0[u].z); p[3] = f2b(xf0[u].w);
      p[4] = f2b(xf1[u].x); p[5] = f2b(xf1[u].y);
      p[6] = f2b(xf1[u].z); p[7] = f2b(xf1[u].w);
      *(s16x8*)&Bs[row * 64 + ((k8 ^ (row & 7)) << 3)] = p;
#pragma unroll
      for (int j = 0; j < 8; ++j) {
        int d = k8 * 8 + j;
        Ts[d * 136 + (row ^ (d & 32))] = p[j];
      }
    }
#pragma unroll
    for (int i = 0; i < 2; ++i) {
      int chunk = w * 2 + i;
      int row = chunk * 8 + (lane >> 3);
      gll16(W1tg + (size_t)row * D_ + k0 + swzk * 8, As + chunk * 512);
    }
    __syncthreads();
    if (k0 + 64 < D_) {
#pragma unroll
      for (int u = 0; u < 2; ++u) {
        int c = tid * 2 + u;
        int row = c >> 3, k8 = c & 7;
        const float* gp = xb + (size_t)(t0 + row) * D_ + (k0 + 64) + k8 * 8;
        xf0[u] = *(const float4*)gp;
        xf1[u] = *(const float4*)(gp + 4);
      }
    }
#pragma unroll
    for (int kk = 0; kk < 2; ++kk) {
      const int sl = kk ? sl1 : sl0;
      s16x8 a[4], b[2];
#pragma unroll
      for (int mf = 0; mf < 4; ++mf)
        a[mf] = *(const s16x8*)&As[(wva * 64 + mf * 16 + lr) * 64 + sl];
#pragma unroll
      for (int nf = 0; nf < 2; ++nf)
        b[nf] = *(const s16x8*)&Bs[(wvt * 32 + nf * 16 + lr) * 64 + sl];
#pragma unroll
      for (int mf = 0; mf < 4; ++mf)
#pragma unroll
        for (int nf = 0; nf < 2; ++nf)
          acc[mf][nf] = __builtin_amdgcn_mfma_f32_16x16x32_bf16(
              a[mf], b[nf], acc[mf][nf], 0, 0, 0);
    }
#pragma unroll
    for (int u = 0; u < 2; ++u) {
      int task = tid + u * 512;
      int dd = task >> 4, t8 = task & 15;
      nts16x8(&Xtb[(size_t)(k0 + dd) * T_ + t0 + t8 * 8],
              *(const s16x8*)&Ts[dd * 136 + ((t8 ^ ((dd >> 3) & 4)) << 3)]);
    }
  }

  __syncthreads();
#pragma unroll
  for (int mf = 0; mf < 4; ++mf)
#pragma unroll
    for (int nf = 0; nf < 2; ++nf) {
      int ml = wva * 64 + mf * 16 + lq * 4;
      int nl = wvt * 32 + nf * 16 + lr;
      s16x4 pk;
#pragma unroll
      for (int qq = 0; qq < 4; ++qq) pk[qq] = f2b(tanhf(acc[mf][nf][qq]));
      int slot = (ml >> 3) ^ (nl & 7);
      *(s16x4*)&Hs[nl * 128 + (slot << 3) + (ml & 7)] = pk;
    }
  __syncthreads();

  const int wvt2 = w >> 2, wvs = w & 3;
  for (int si = 0; si < 8; ++si) {
    const int s0 = si * 128;
#pragma unroll
    for (int i = 0; i < 4; ++i) {
      int c = w * 4 + i;
      int row = 4 * c + (lane >> 4);
      gll16(W2tg + (size_t)(s0 + row) * A_ + (((lane & 15) ^ (row & 7)) << 3),
            B2 + c * 512);
    }
    __syncthreads();
    f32x4 ac2[4][2] = {};
#pragma unroll
    for (int kk = 0; kk < 4; ++kk) {
      s16x8 a[4], b[2];
#pragma unroll
      for (int mf = 0; mf < 4; ++mf) {
        int row = wvt2 * 64 + mf * 16 + lr;
        a[mf] = *(const s16x8*)&Hs[row * 128 + (((kk * 4 + lq) ^ sxl) << 3)];
      }
#pragma unroll
      for (int nf = 0; nf < 2; ++nf) {
        int row = wvs * 32 + nf * 16 + lr;
        b[nf] = *(const s16x8*)&B2[row * 128 + (((kk * 4 + lq) ^ sxl) << 3)];
      }
#pragma unroll
      for (int mf = 0; mf < 4; ++mf)
#pragma unroll
        for (int nf = 0; nf < 2; ++nf)
          ac2[mf][nf] = __builtin_amdgcn_mfma_f32_16x16x32_bf16(
              a[mf], b[nf], ac2[mf][nf], 0, 0, 0);
    }
    __syncthreads();
    float psum[2] = {0.f, 0.f};
#pragma unroll
    for (int mf = 0; mf < 4; ++mf)
#pragma unroll
      for (int nf = 0; nf < 2; ++nf) {
        int ml = wvt2 * 64 + mf * 16 + lq * 4;
        int nl = wvs * 32 + nf * 16 + lr;
        s16x4 pk;
#pragma unroll
        for (int qq = 0; qq < 4; ++qq) {
          float v = __expf(ac2[mf][nf][qq]);
          pk[qq] = f2b(v);
          psum[nf] += b2f(pk[qq]);
        }
        *(s16x4*)&B2[nl * 136 + ml] = pk;
      }
#pragma unroll
    for (int nf = 0; nf < 2; ++nf) {
      psum[nf] += __shfl_xor(psum[nf], 16);
      psum[nf] += __shfl_xor(psum[nf], 32);
    }
    if (lq == 0) {
#pragma unroll
      for (int nf = 0; nf < 2; ++nf)
        atomicAdd(&rsb[s0 + wvs * 32 + nf * 16 + lr], psum[nf]);
    }
    __syncthreads();
#pragma unroll
    for (int it = 0; it < 4; ++it) {
      int row = it * 32 + (tid >> 4);
      int col = (tid & 15) * 8;
      nts16x8(&Stb[(size_t)(s0 + row) * T_ + t0 + col],
              *(const s16x8*)&B2[row * 136 + col]);
    }
    __syncthreads();
  }
}

// ---------------------------------------------------------------------------
// transpose + fp32->bf16 (W1/W2 only).
// ---------------------------------------------------------------------------
__global__ __launch_bounds__(256)
void transpose_cvt(const float* __restrict__ src, short* __restrict__ dst,
                   int R, int C) {
  __shared__ float sh[64][65];
  const int tid = threadIdx.x;
  const float* s = src + (size_t)blockIdx.z * R * C;
  short* d = dst + (size_t)blockIdx.z * R * C;
  const int r0 = blockIdx.y * 64, c0 = blockIdx.x * 64;
#pragma unroll
  for (int u = 0; u < 4; ++u) {
    int e = tid + u * 256;
    int rr = e >> 4, cc4 = (e & 15) * 4;
    float4 v = *(const float4*)&s[(size_t)(r0 + rr) * C + c0 + cc4];
    sh[rr][cc4 + 0] = v.x;
    sh[rr][cc4 + 1] = v.y;
    sh[rr][cc4 + 2] = v.z;
    sh[rr][cc4 + 3] = v.w;
  }
  __syncthreads();
#pragma unroll
  for (int u = 0; u < 4; ++u) {
    int e = tid + u * 256;
    int dr = e >> 4, tc4 = (e & 15) * 4;
    s16x4 pk;
#pragma unroll
    for (int j = 0; j < 4; ++j) pk[j] = f2b(sh[tc4 + j][dr]);
    *(s16x4*)&d[(size_t)(c0 + dr) * R + r0 + tc4] = pk;
  }
}

extern "C" void kernel_launch(void* const* d_in, const int* in_sizes, int n_in,
                              void* d_out, int out_size, void* d_ws, size_t ws_size,
                              hipStream_t stream) {
  const float* x  = (const float*)d_in[0];   // [B,T,D]
  const float* W1 = (const float*)d_in[1];   // [D,A]
  const float* W2 = (const float*)d_in[2];   // [A,T]
  float* out = (float*)d_out;                // [B,T,D] fp32

  // ws (shorts): xt[B,D,T] | W1t[A,D] | W2t[T,A] | rs[B*T fp32] | St[nb,T,T]
  short* xt  = (short*)d_ws;
  short* W1t = xt + (size_t)B_ * D_ * T_;
  short* W2t = W1t + (size_t)A_ * D_;
  float* rs  = (float*)(W2t + (size_t)T_ * A_);
  short* St  = (short*)(rs + (size_t)B_ * T_);
  size_t fixed_bytes = (size_t)((char*)St - (char*)xt);
  long avail = (long)ws_size - (long)fixed_bytes;
  long per_b = (long)T_ * T_ * sizeof(short);
  int chunk = (int)(avail > 0 ? avail / per_b : 0);
  if (chunk > B_) chunk = B_;
  if (chunk < 1) chunk = 1;

  hipMemsetAsync(rs, 0, (size_t)B_ * T_ * sizeof(float), stream);

  transpose_cvt<<<dim3(A_ / 64, D_ / 64, 1), 256, 0, stream>>>(W1, W1t, D_, A_);
  transpose_cvt<<<dim3(T_ / 64, A_ / 64, 1), 256, 0, stream>>>(W2, W2t, A_, T_);

  for (int b0 = 0; b0 < B_; b0 += chunk) {
    int nb = B_ - b0; if (nb > chunk) nb = chunk;
    g12<<<8 * nb, 512, 0, stream>>>(
        W1t, x + (size_t)b0 * T_ * D_, W2t, St,
        rs + (size_t)b0 * T_, xt + (size_t)b0 * (size_t)D_ * T_, nb);
    g4_div<<<12 * nb, 512, 0, stream>>>(
        St, xt + (size_t)b0 * (size_t)D_ * T_, rs + (size_t)b0 * T_,
        out + (size_t)b0 * (size_t)T_ * D_);
  }
}